// Round 6
// baseline (621.042 us; speedup 1.0000x reference)
//
#include <hip/hip_runtime.h>
#include <hip/hip_fp16.h>

// ---------------------------------------------------------------------------
// GCN: per-call CSR build (pack+hist / 3-phase scan / XCD-bucketed scatter),
// then 3x (GEMM -> CSR-SpMM). BN finalize+affine+ReLU fused into next GEMM.
// H (gather table) fp16. CSR entries packed to 4B (u16 col | fp16 w).
// Non-temporal loads/stores on all streaming paths so L2 keeps (a) dirty
// scatter lines until they fill, (b) the H gather table during SpMM.
// b0/b1 dropped (cancel in BN mean-subtraction).
// ---------------------------------------------------------------------------

constexpr int   N_NODES  = 50000;
constexpr int   E_EDGES  = 1600000;
constexpr float BN_EPS   = 1e-5f;
constexpr int   SCAN_BLK = (N_NODES + 255) / 256;     // 196
constexpr int   ROWS_PER_BUCKET = (N_NODES + 7) / 8;  // 6250
constexpr int   SC_BLOCKS = 1024;                     // multiple of 8

typedef float vf4 __attribute__((ext_vector_type(4)));
typedef float vf2 __attribute__((ext_vector_type(2)));
typedef int   vi4 __attribute__((ext_vector_type(4)));

__device__ __forceinline__ float dec_w(unsigned u) {
  return __half2float(__ushort_as_half((unsigned short)(u >> 16)));
}

// ========================= pack + hist =========================
// packed[e] = col | (fp16(w) << 16); deg histogram via atomics.
__global__ __launch_bounds__(256) void pack_hist_ker(const int* __restrict__ rows,
                                                     const int* __restrict__ cols,
                                                     const float* __restrict__ ew,
                                                     int* __restrict__ deg,
                                                     unsigned* __restrict__ packed) {
  const int q = blockIdx.x * 256 + threadIdx.x;
  if (q >= E_EDGES / 4) return;
  const vi4 r4 = __builtin_nontemporal_load((const vi4*)rows + q);
  const vi4 c4 = __builtin_nontemporal_load((const vi4*)cols + q);
  const vf4 w4 = __builtin_nontemporal_load((const vf4*)ew + q);
  atomicAdd(&deg[r4[0]], 1);
  atomicAdd(&deg[r4[1]], 1);
  atomicAdd(&deg[r4[2]], 1);
  atomicAdd(&deg[r4[3]], 1);
  vi4 p;
  p[0] = c4[0] | ((int)__half_as_ushort(__float2half_rn(w4[0])) << 16);
  p[1] = c4[1] | ((int)__half_as_ushort(__float2half_rn(w4[1])) << 16);
  p[2] = c4[2] | ((int)__half_as_ushort(__float2half_rn(w4[2])) << 16);
  p[3] = c4[3] | ((int)__half_as_ushort(__float2half_rn(w4[3])) << 16);
  __builtin_nontemporal_store(p, (vi4*)packed + q);
}

// ========================= scan =========================
__global__ __launch_bounds__(256) void scan1_ker(const int* __restrict__ deg,
                                                 int* __restrict__ partial) {
  const int r = blockIdx.x * 256 + threadIdx.x;
  int v = (r < N_NODES) ? deg[r] : 0;
#pragma unroll
  for (int o = 32; o > 0; o >>= 1) v += __shfl_down(v, o, 64);
  __shared__ int sh[4];
  if ((threadIdx.x & 63) == 0) sh[threadIdx.x >> 6] = v;
  __syncthreads();
  if (threadIdx.x == 0) partial[blockIdx.x] = sh[0] + sh[1] + sh[2] + sh[3];
}

__global__ __launch_bounds__(256) void scan2_ker(const int* __restrict__ partial,
                                                 int* __restrict__ blockoff) {
  const int t = threadIdx.x;
  int v = (t < SCAN_BLK) ? partial[t] : 0;
  __shared__ int sh[256];
  sh[t] = v;
  __syncthreads();
  for (int off = 1; off < 256; off <<= 1) {
    int u = (t >= off) ? sh[t - off] : 0;
    __syncthreads();
    sh[t] += u;
    __syncthreads();
  }
  blockoff[t] = (t == 0) ? 0 : sh[t - 1];
}

__global__ __launch_bounds__(256) void scan3_ker(int* __restrict__ deg,
                                                 const int* __restrict__ blockoff,
                                                 int* __restrict__ rowptr) {
  const int t = threadIdx.x;
  const int r = blockIdx.x * 256 + t;
  const int v = (r < N_NODES) ? deg[r] : 0;
  __shared__ int sh[256];
  sh[t] = v;
  __syncthreads();
  for (int off = 1; off < 256; off <<= 1) {
    int u = (t >= off) ? sh[t - off] : 0;
    __syncthreads();
    sh[t] += u;
    __syncthreads();
  }
  const int base = blockoff[blockIdx.x];
  if (r < N_NODES) {
    rowptr[r] = base + sh[t] - v;
    deg[r] = 0;
  }
  if (r == N_NODES - 1) rowptr[N_NODES] = base + sh[t];
}

// ========================= scatter (XCD-bucketed) =========================
// Blocks with blockIdx%8==p scatter only rows of bucket p; with nt streaming
// reads, the bucket's ~800KB se window stays dirty-resident in that XCD's L2
// so the 4B writes merge into full lines.
__global__ __launch_bounds__(256) void scatter_ker(const int* __restrict__ rows,
                                                   const unsigned* __restrict__ packed,
                                                   const int* __restrict__ rowptr,
                                                   int* __restrict__ cursor,
                                                   unsigned* __restrict__ se) {
  const int xcd    = blockIdx.x & 7;
  const int sub    = blockIdx.x >> 3;
  const int nsub   = gridDim.x >> 3;
  const int rlo    = xcd * ROWS_PER_BUCKET;
  const int rhi    = min(rlo + ROWS_PER_BUCKET, N_NODES);
  const int tcount = nsub * 256;
  const int tid    = sub * 256 + threadIdx.x;
  for (int q = tid; q < E_EDGES / 4; q += tcount) {
    const vi4 r4 = __builtin_nontemporal_load((const vi4*)rows + q);
    const vi4 p4 = __builtin_nontemporal_load((const vi4*)packed + q);
#pragma unroll
    for (int i = 0; i < 4; ++i) {
      const int r = r4[i];
      if (r >= rlo && r < rhi) {
        const int pos = rowptr[r] + atomicAdd(&cursor[r], 1);
        se[pos] = (unsigned)p4[i];
      }
    }
  }
}

// ========================= GEMM =========================
// H[N][FOUT](fp16) = act(X)[N][128](fp32) @ W[128][FOUT].
// act (FUSE): BN finalize from raw stats (computed per-block) + affine + ReLU.
template <int FOUT, int ROWS, bool FUSE>
__global__ __launch_bounds__(256) void gemm_ker(const float* __restrict__ X,
                                                const float* __restrict__ W,
                                                __half* __restrict__ H,
                                                const float* __restrict__ stats,
                                                const float* __restrict__ g,
                                                const float* __restrict__ be) {
  constexpr int FQ    = FOUT / 4;
  constexpr int RQ    = ROWS / 4;
  constexpr int UNITS = FQ * RQ;
  static_assert(UNITS <= 256, "tile too big");

  __shared__ float Ws[128 * FOUT];
  __shared__ float Xs[ROWS][129];
  __shared__ float ssc[128], ssh[128];

  const int tid  = threadIdx.x;
  const int row0 = blockIdx.x * ROWS;

  if constexpr (FUSE) {
    if (tid < 128) {
      const float mean = stats[tid] * (1.0f / N_NODES);
      const float var  = stats[128 + tid] * (1.0f / N_NODES) - mean * mean;
      const float sc   = g[tid] * rsqrtf(var + BN_EPS);
      ssc[tid] = sc;
      ssh[tid] = be[tid] - mean * sc;
    }
    __syncthreads();
  }

  for (int i = tid; i < 128 * FOUT; i += 256) Ws[i] = W[i];

  for (int q = tid; q < ROWS * 32; q += 256) {
    const int r  = q >> 5;
    const int k4 = (q & 31) * 4;
    int gr = row0 + r;
    if (gr >= N_NODES) gr = N_NODES - 1;
    vf4 v = __builtin_nontemporal_load((const vf4*)(X + (long)gr * 128 + k4));
    if constexpr (FUSE) {
      v[0] = fmaxf(v[0] * ssc[k4 + 0] + ssh[k4 + 0], 0.f);
      v[1] = fmaxf(v[1] * ssc[k4 + 1] + ssh[k4 + 1], 0.f);
      v[2] = fmaxf(v[2] * ssc[k4 + 2] + ssh[k4 + 2], 0.f);
      v[3] = fmaxf(v[3] * ssc[k4 + 3] + ssh[k4 + 3], 0.f);
    }
    Xs[r][k4 + 0] = v[0]; Xs[r][k4 + 1] = v[1];
    Xs[r][k4 + 2] = v[2]; Xs[r][k4 + 3] = v[3];
  }
  __syncthreads();

  if (tid < UNITS) {
    const int fq = (tid % FQ) * 4;
    const int rg = (tid / FQ) * 4;
    float4 a0 = {0, 0, 0, 0}, a1 = a0, a2 = a0, a3 = a0;
#pragma unroll 8
    for (int k = 0; k < 128; ++k) {
      const float4 wv = *(const float4*)(Ws + k * FOUT + fq);
      const float x0 = Xs[rg + 0][k];
      const float x1 = Xs[rg + 1][k];
      const float x2 = Xs[rg + 2][k];
      const float x3 = Xs[rg + 3][k];
      a0.x += x0 * wv.x; a0.y += x0 * wv.y; a0.z += x0 * wv.z; a0.w += x0 * wv.w;
      a1.x += x1 * wv.x; a1.y += x1 * wv.y; a1.z += x1 * wv.z; a1.w += x1 * wv.w;
      a2.x += x2 * wv.x; a2.y += x2 * wv.y; a2.z += x2 * wv.z; a2.w += x2 * wv.w;
      a3.x += x3 * wv.x; a3.y += x3 * wv.y; a3.z += x3 * wv.z; a3.w += x3 * wv.w;
    }
    const float4 accs[4] = {a0, a1, a2, a3};
#pragma unroll
    for (int i = 0; i < 4; ++i) {
      const int gr = row0 + rg + i;
      if (gr < N_NODES) {
        __half2 p0 = __floats2half2_rn(accs[i].x, accs[i].y);
        __half2 p1 = __floats2half2_rn(accs[i].z, accs[i].w);
        __half2* dst = (__half2*)(H + (long)gr * FOUT + fq);
        dst[0] = p0;   // cached: H must stay L2-resident for the gather
        dst[1] = p1;
      }
    }
  }
}

// ========================= CSR SpMM =========================
__global__ __launch_bounds__(256) void spmm_csr128_ker(const int* __restrict__ rowptr,
                                                       const unsigned* __restrict__ se,
                                                       const __half* __restrict__ H,
                                                       float* __restrict__ A) {
  const int gid  = blockIdx.x * 256 + threadIdx.x;
  const int lane = threadIdx.x & 63;
  const int wid  = __builtin_amdgcn_readfirstlane(gid >> 6);
  if (wid >= N_NODES) return;
  const int beg = rowptr[wid];
  const int end = rowptr[wid + 1];
  const __half2* __restrict__ Hl = (const __half2*)H + lane;  // row stride 64
  float acc0 = 0.f, acc1 = 0.f;
  int e = beg;
  for (; e + 4 <= end; e += 4) {
    const unsigned u0 = __builtin_nontemporal_load(se + e + 0);
    const unsigned u1 = __builtin_nontemporal_load(se + e + 1);
    const unsigned u2 = __builtin_nontemporal_load(se + e + 2);
    const unsigned u3 = __builtin_nontemporal_load(se + e + 3);
    const float2 v0 = __half22float2(Hl[(long)(u0 & 0xFFFF) * 64]);
    const float2 v1 = __half22float2(Hl[(long)(u1 & 0xFFFF) * 64]);
    const float2 v2 = __half22float2(Hl[(long)(u2 & 0xFFFF) * 64]);
    const float2 v3 = __half22float2(Hl[(long)(u3 & 0xFFFF) * 64]);
    const float w0 = dec_w(u0), w1 = dec_w(u1), w2 = dec_w(u2), w3 = dec_w(u3);
    acc0 += w0 * v0.x; acc1 += w0 * v0.y;
    acc0 += w1 * v1.x; acc1 += w1 * v1.y;
    acc0 += w2 * v2.x; acc1 += w2 * v2.y;
    acc0 += w3 * v3.x; acc1 += w3 * v3.y;
  }
  for (; e < end; ++e) {
    const unsigned u = __builtin_nontemporal_load(se + e);
    const float2 v = __half22float2(Hl[(long)(u & 0xFFFF) * 64]);
    const float  w = dec_w(u);
    acc0 += w * v.x; acc1 += w * v.y;
  }
  vf2 o; o[0] = acc0; o[1] = acc1;
  __builtin_nontemporal_store(o, (vf2*)(A + (long)wid * 128 + lane * 2));
}

__global__ __launch_bounds__(256) void spmm_csr40_ker(const int* __restrict__ rowptr,
                                                      const unsigned* __restrict__ se,
                                                      const __half* __restrict__ H,
                                                      const float* __restrict__ b,
                                                      float* __restrict__ out) {
  const int gid  = blockIdx.x * 256 + threadIdx.x;
  const int lane = threadIdx.x & 63;
  const int wid  = __builtin_amdgcn_readfirstlane(gid >> 6);
  if (wid >= N_NODES) return;
  const int beg = rowptr[wid];
  const int end = rowptr[wid + 1];
  const bool act = lane < 40;
  const int  l   = act ? lane : 0;
  float acc = 0.f;
  int e = beg;
  for (; e + 4 <= end; e += 4) {
    const unsigned u0 = __builtin_nontemporal_load(se + e + 0);
    const unsigned u1 = __builtin_nontemporal_load(se + e + 1);
    const unsigned u2 = __builtin_nontemporal_load(se + e + 2);
    const unsigned u3 = __builtin_nontemporal_load(se + e + 3);
    const float v0 = __half2float(H[(long)(u0 & 0xFFFF) * 40 + l]);
    const float v1 = __half2float(H[(long)(u1 & 0xFFFF) * 40 + l]);
    const float v2 = __half2float(H[(long)(u2 & 0xFFFF) * 40 + l]);
    const float v3 = __half2float(H[(long)(u3 & 0xFFFF) * 40 + l]);
    acc += dec_w(u0) * v0;
    acc += dec_w(u1) * v1;
    acc += dec_w(u2) * v2;
    acc += dec_w(u3) * v3;
  }
  for (; e < end; ++e) {
    const unsigned u = __builtin_nontemporal_load(se + e);
    acc += dec_w(u) * __half2float(H[(long)(u & 0xFFFF) * 40 + l]);
  }
  if (act) __builtin_nontemporal_store(acc + b[lane], out + (long)wid * 40 + lane);
}

// ========================= BatchNorm stats =========================
constexpr int BN_BLOCKS   = 512;
constexpr int BN_ROWS_PER = (N_NODES + BN_BLOCKS - 1) / BN_BLOCKS;  // 98

__global__ __launch_bounds__(256) void bn_stats_ker(const float* __restrict__ A,
                                                    float* __restrict__ stats) {
  const int tid = threadIdx.x;
  const int c   = tid & 127;
  const int rs  = tid >> 7;
  const int r0  = blockIdx.x * BN_ROWS_PER;
  const int re  = min(r0 + BN_ROWS_PER, N_NODES);
  float s = 0.f, sq = 0.f;
  for (int r = r0 + rs; r < re; r += 2) {
    const float v = __builtin_nontemporal_load(A + (long)r * 128 + c);
    s += v; sq += v * v;
  }
  atomicAdd(&stats[c], s);
  atomicAdd(&stats[128 + c], sq);
}

// ---------------------------------------------------------------------------
extern "C" void kernel_launch(void* const* d_in, const int* in_sizes, int n_in,
                              void* d_out, int out_size, void* d_ws, size_t ws_size,
                              hipStream_t stream) {
  const float* x    = (const float*)d_in[0];
  const int*   erow = (const int*)d_in[1];
  const int*   ecol = (const int*)d_in[2];
  const float* ew   = (const float*)d_in[3];
  const float* W0   = (const float*)d_in[4];
  const float* g0   = (const float*)d_in[6];
  const float* be0  = (const float*)d_in[7];
  const float* W1   = (const float*)d_in[8];
  const float* g1   = (const float*)d_in[10];
  const float* be1  = (const float*)d_in[11];
  const float* W2   = (const float*)d_in[12];
  const float* b2   = (const float*)d_in[13];
  float* out = (float*)d_out;

  // workspace layout (16B-aligned sections)
  float*    agg     = (float*)d_ws;                          // N*128 fp32
  __half*   h       = (__half*)(agg + (long)N_NODES * 128);  // N*128 fp16
  float*    stats0  = (float*)(h + (long)N_NODES * 128);     // 256
  float*    stats1  = stats0 + 256;                          // 256
  int*      rowptr  = (int*)(stats1 + 256);                  // N+1 (pad 50004)
  int*      cursor  = rowptr + 50004;                        // N (deg -> cursor)
  int*      partial = cursor + N_NODES;                      // pad 256
  int*      bloff   = partial + 256;                         // pad 256
  unsigned* packed  = (unsigned*)(bloff + 256);              // E  (16B-aligned)
  unsigned* se      = packed + E_EDGES;                      // E

  const int g_pack    = (E_EDGES / 4 + 255) / 256;  // 1563
  const int g_gemm128 = (N_NODES + 31) / 32;        // 1563
  const int g_gemm40  = (N_NODES + 95) / 96;        // 521
  const int g_spmm    = (N_NODES * 64) / 256;       // 12500

  // ---- zero cursor + both stats up front ----
  hipMemsetAsync(cursor, 0, (size_t)N_NODES * 4, stream);
  hipMemsetAsync(stats0, 0, 512 * 4, stream);

  // ---- CSR build ----
  pack_hist_ker<<<g_pack, 256, 0, stream>>>(erow, ecol, ew, cursor, packed);
  scan1_ker<<<SCAN_BLK, 256, 0, stream>>>(cursor, partial);
  scan2_ker<<<1, 256, 0, stream>>>(partial, bloff);
  scan3_ker<<<SCAN_BLK, 256, 0, stream>>>(cursor, bloff, rowptr);
  scatter_ker<<<SC_BLOCKS, 256, 0, stream>>>(erow, packed, rowptr, cursor, se);

  // ---- layer 0 ----
  gemm_ker<128, 32, false><<<g_gemm128, 256, 0, stream>>>(x, W0, h, nullptr, nullptr, nullptr);
  spmm_csr128_ker<<<g_spmm, 256, 0, stream>>>(rowptr, se, h, agg);
  bn_stats_ker<<<BN_BLOCKS, 256, 0, stream>>>(agg, stats0);

  // ---- layer 1 (BN0 finalize+affine+ReLU fused into GEMM input load) ----
  gemm_ker<128, 32, true><<<g_gemm128, 256, 0, stream>>>(agg, W1, h, stats0, g0, be0);
  spmm_csr128_ker<<<g_spmm, 256, 0, stream>>>(rowptr, se, h, agg);
  bn_stats_ker<<<BN_BLOCKS, 256, 0, stream>>>(agg, stats1);

  // ---- layer 2 (BN1 fused into GEMM, bias b2 fused into SpMM) ----
  gemm_ker<40, 96, true><<<g_gemm40, 256, 0, stream>>>(agg, W2, h, stats1, g1, be1);
  spmm_csr40_ker<<<g_spmm, 256, 0, stream>>>(rowptr, se, h, b2, out);
}

// Round 7
// 477.779 us; speedup vs baseline: 1.2999x; 1.2999x over previous
//
#include <hip/hip_runtime.h>
#include <hip/hip_fp16.h>

// ---------------------------------------------------------------------------
// GCN: per-call CSR build via LDS-binned two-phase partition (no random
// scatter, no 50K-cursor atomics), then 3x (GEMM -> CSR-SpMM).
// BN finalize+affine+ReLU fused into next GEMM. H gather table fp16.
// CSR entries packed to 4B (u16 col | fp16 w). b0/b1 dropped (cancel in BN).
// ---------------------------------------------------------------------------

constexpr int   N_NODES   = 50000;
constexpr int   E_EDGES   = 1600000;
constexpr float BN_EPS    = 1e-5f;
constexpr int   K_BUCKETS = (N_NODES + 255) / 256;   // 196 (256 rows each)
constexpr int   BCAP      = 10240;   // ebuf entries per bucket (mean 8192, 22 sigma)
constexpr int   CHUNK     = 4096;    // edges per partition block
constexpr int   PART_BLK  = (E_EDGES + CHUNK - 1) / CHUNK;  // 391

typedef float vf2 __attribute__((ext_vector_type(2)));

__device__ __forceinline__ float dec_w(unsigned u) {
  return __half2float(__ushort_as_half((unsigned short)(u >> 16)));
}

// ========================= partition phase A =========================
// Bin a 4096-edge chunk by bucket (row>>8) in LDS, then write each bucket's
// run contiguously into its ebuf region (one cursor bump per bucket).
// Runs are dense -> at most 2 blocks share any cache line.
__global__ __launch_bounds__(256) void partA_ker(const int* __restrict__ rows,
                                                 const int* __restrict__ cols,
                                                 const float* __restrict__ ew,
                                                 int* __restrict__ gcursor,
                                                 int2* __restrict__ ebuf) {
  __shared__ int  cnt[256], cnt2[256], sc[256], offs[256], gbase[256];
  __shared__ int2 buf[CHUNK];
  const int tid = threadIdx.x;
  cnt[tid] = 0; cnt2[tid] = 0;
  __syncthreads();

  const int e0   = blockIdx.x * CHUNK;
  const int ecnt = min(CHUNK, E_EDGES - e0);

  // pass 1: count per bucket
  for (int i = tid; i < ecnt; i += 256)
    atomicAdd(&cnt[rows[e0 + i] >> 8], 1);
  __syncthreads();

  // inclusive scan -> exclusive offsets
  sc[tid] = cnt[tid];
  __syncthreads();
  for (int o = 1; o < 256; o <<= 1) {
    int u = (tid >= o) ? sc[tid - o] : 0;
    __syncthreads();
    sc[tid] += u;
    __syncthreads();
  }
  offs[tid] = sc[tid] - cnt[tid];
  // one global cursor bump per non-empty bucket
  if (tid < K_BUCKETS && cnt[tid] > 0)
    gbase[tid] = atomicAdd(&gcursor[tid], cnt[tid]);
  __syncthreads();

  // pass 2: place into LDS buffer ordered by bucket (rows are L2-hot)
  for (int i = tid; i < ecnt; i += 256) {
    const int   r = rows[e0 + i];
    const int   c = cols[e0 + i];
    const float w = ew[e0 + i];
    const int   b = r >> 8;
    const int   p = offs[b] + atomicAdd(&cnt2[b], 1);
    int2 v;
    v.x = c | ((int)__half_as_ushort(__float2half_rn(w)) << 16);
    v.y = r;
    buf[p] = v;
  }
  __syncthreads();

  // flush: contiguous runs per bucket
  for (int i = tid; i < ecnt; i += 256) {
    const int2 v   = buf[i];
    const int  b   = v.y >> 8;
    const int  idx = gbase[b] + (i - offs[b]);
    if (idx < BCAP) ebuf[(long)b * BCAP + idx] = v;  // overflow guard (22 sigma)
  }
}

// ========================= bucket-base scan =========================
__global__ __launch_bounds__(256) void bscan_ker(const int* __restrict__ gcursor,
                                                 int* __restrict__ bbase,
                                                 int* __restrict__ rowptr) {
  const int t = threadIdx.x;
  const int v = (t < K_BUCKETS) ? gcursor[t] : 0;
  __shared__ int sh[256];
  sh[t] = v;
  __syncthreads();
  for (int o = 1; o < 256; o <<= 1) {
    int u = (t >= o) ? sh[t - o] : 0;
    __syncthreads();
    sh[t] += u;
    __syncthreads();
  }
  bbase[t] = sh[t] - v;  // exclusive
  if (t == 0) rowptr[N_NODES] = E_EDGES;
}

// ========================= partition phase B =========================
// One block per bucket: per-row count+scan in LDS, write rowptr, place final
// 4B entries into the bucket's exclusive contiguous se window (~33KB) ->
// single-writer region, full line merging.
__global__ __launch_bounds__(256) void partB_ker(const int* __restrict__ gcursor,
                                                 const int* __restrict__ bbase,
                                                 const int2* __restrict__ ebuf,
                                                 unsigned* __restrict__ se,
                                                 int* __restrict__ rowptr) {
  const int b    = blockIdx.x;
  const int tid  = threadIdx.x;
  const int cntb = min(gcursor[b], BCAP);
  const int base = bbase[b];
  __shared__ int rcnt[256], roff[256], rcur[256], sh[256];
  rcnt[tid] = 0; rcur[tid] = 0;
  __syncthreads();

  const int2* __restrict__ src = ebuf + (long)b * BCAP;
  for (int i = tid; i < cntb; i += 256)
    atomicAdd(&rcnt[src[i].y & 255], 1);
  __syncthreads();

  sh[tid] = rcnt[tid];
  __syncthreads();
  for (int o = 1; o < 256; o <<= 1) {
    int u = (tid >= o) ? sh[tid - o] : 0;
    __syncthreads();
    sh[tid] += u;
    __syncthreads();
  }
  roff[tid] = sh[tid] - rcnt[tid];
  const int grow = b * 256 + tid;
  if (grow < N_NODES) rowptr[grow] = base + roff[tid];
  __syncthreads();

  for (int i = tid; i < cntb; i += 256) {
    const int2 v  = src[i];
    const int  rl = v.y & 255;
    const int  p  = roff[rl] + atomicAdd(&rcur[rl], 1);
    se[base + p] = (unsigned)v.x;
  }
}

// ========================= GEMM =========================
// H[N][FOUT](fp16) = act(X)[N][128](fp32) @ W[128][FOUT].
// act (FUSE): BN finalize from raw stats (computed per-block) + affine + ReLU.
template <int FOUT, int ROWS, bool FUSE>
__global__ __launch_bounds__(256) void gemm_ker(const float* __restrict__ X,
                                                const float* __restrict__ W,
                                                __half* __restrict__ H,
                                                const float* __restrict__ stats,
                                                const float* __restrict__ g,
                                                const float* __restrict__ be) {
  constexpr int FQ    = FOUT / 4;
  constexpr int RQ    = ROWS / 4;
  constexpr int UNITS = FQ * RQ;
  static_assert(UNITS <= 256, "tile too big");

  __shared__ float Ws[128 * FOUT];
  __shared__ float Xs[ROWS][129];
  __shared__ float ssc[128], ssh[128];

  const int tid  = threadIdx.x;
  const int row0 = blockIdx.x * ROWS;

  if constexpr (FUSE) {
    if (tid < 128) {
      const float mean = stats[tid] * (1.0f / N_NODES);
      const float var  = stats[128 + tid] * (1.0f / N_NODES) - mean * mean;
      const float sc   = g[tid] * rsqrtf(var + BN_EPS);
      ssc[tid] = sc;
      ssh[tid] = be[tid] - mean * sc;
    }
    __syncthreads();
  }

  for (int i = tid; i < 128 * FOUT; i += 256) Ws[i] = W[i];

  for (int q = tid; q < ROWS * 32; q += 256) {
    const int r  = q >> 5;
    const int k4 = (q & 31) * 4;
    int gr = row0 + r;
    if (gr >= N_NODES) gr = N_NODES - 1;
    float4 v = *(const float4*)(X + (long)gr * 128 + k4);
    if constexpr (FUSE) {
      v.x = fmaxf(v.x * ssc[k4 + 0] + ssh[k4 + 0], 0.f);
      v.y = fmaxf(v.y * ssc[k4 + 1] + ssh[k4 + 1], 0.f);
      v.z = fmaxf(v.z * ssc[k4 + 2] + ssh[k4 + 2], 0.f);
      v.w = fmaxf(v.w * ssc[k4 + 3] + ssh[k4 + 3], 0.f);
    }
    Xs[r][k4 + 0] = v.x; Xs[r][k4 + 1] = v.y;
    Xs[r][k4 + 2] = v.z; Xs[r][k4 + 3] = v.w;
  }
  __syncthreads();

  if (tid < UNITS) {
    const int fq = (tid % FQ) * 4;
    const int rg = (tid / FQ) * 4;
    float4 a0 = {0, 0, 0, 0}, a1 = a0, a2 = a0, a3 = a0;
#pragma unroll 8
    for (int k = 0; k < 128; ++k) {
      const float4 wv = *(const float4*)(Ws + k * FOUT + fq);
      const float x0 = Xs[rg + 0][k];
      const float x1 = Xs[rg + 1][k];
      const float x2 = Xs[rg + 2][k];
      const float x3 = Xs[rg + 3][k];
      a0.x += x0 * wv.x; a0.y += x0 * wv.y; a0.z += x0 * wv.z; a0.w += x0 * wv.w;
      a1.x += x1 * wv.x; a1.y += x1 * wv.y; a1.z += x1 * wv.z; a1.w += x1 * wv.w;
      a2.x += x2 * wv.x; a2.y += x2 * wv.y; a2.z += x2 * wv.z; a2.w += x2 * wv.w;
      a3.x += x3 * wv.x; a3.y += x3 * wv.y; a3.z += x3 * wv.z; a3.w += x3 * wv.w;
    }
    const float4 accs[4] = {a0, a1, a2, a3};
#pragma unroll
    for (int i = 0; i < 4; ++i) {
      const int gr = row0 + rg + i;
      if (gr < N_NODES) {
        __half2 p0 = __floats2half2_rn(accs[i].x, accs[i].y);
        __half2 p1 = __floats2half2_rn(accs[i].z, accs[i].w);
        __half2* dst = (__half2*)(H + (long)gr * FOUT + fq);
        dst[0] = p0;   // cached: H must stay L2-resident for the gather
        dst[1] = p1;
      }
    }
  }
}

// ========================= CSR SpMM =========================
__global__ __launch_bounds__(256) void spmm_csr128_ker(const int* __restrict__ rowptr,
                                                       const unsigned* __restrict__ se,
                                                       const __half* __restrict__ H,
                                                       float* __restrict__ A) {
  const int gid  = blockIdx.x * 256 + threadIdx.x;
  const int lane = threadIdx.x & 63;
  const int wid  = __builtin_amdgcn_readfirstlane(gid >> 6);
  if (wid >= N_NODES) return;
  const int beg = rowptr[wid];
  const int end = rowptr[wid + 1];
  const __half2* __restrict__ Hl = (const __half2*)H + lane;  // row stride 64
  float acc0 = 0.f, acc1 = 0.f;
  int e = beg;
  for (; e + 4 <= end; e += 4) {
    const unsigned u0 = __builtin_nontemporal_load(se + e + 0);
    const unsigned u1 = __builtin_nontemporal_load(se + e + 1);
    const unsigned u2 = __builtin_nontemporal_load(se + e + 2);
    const unsigned u3 = __builtin_nontemporal_load(se + e + 3);
    const float2 v0 = __half22float2(Hl[(long)(u0 & 0xFFFF) * 64]);
    const float2 v1 = __half22float2(Hl[(long)(u1 & 0xFFFF) * 64]);
    const float2 v2 = __half22float2(Hl[(long)(u2 & 0xFFFF) * 64]);
    const float2 v3 = __half22float2(Hl[(long)(u3 & 0xFFFF) * 64]);
    const float w0 = dec_w(u0), w1 = dec_w(u1), w2 = dec_w(u2), w3 = dec_w(u3);
    acc0 += w0 * v0.x; acc1 += w0 * v0.y;
    acc0 += w1 * v1.x; acc1 += w1 * v1.y;
    acc0 += w2 * v2.x; acc1 += w2 * v2.y;
    acc0 += w3 * v3.x; acc1 += w3 * v3.y;
  }
  for (; e < end; ++e) {
    const unsigned u = __builtin_nontemporal_load(se + e);
    const float2 v = __half22float2(Hl[(long)(u & 0xFFFF) * 64]);
    const float  w = dec_w(u);
    acc0 += w * v.x; acc1 += w * v.y;
  }
  *(float2*)(A + (long)wid * 128 + lane * 2) = make_float2(acc0, acc1);
}

__global__ __launch_bounds__(256) void spmm_csr40_ker(const int* __restrict__ rowptr,
                                                      const unsigned* __restrict__ se,
                                                      const __half* __restrict__ H,
                                                      const float* __restrict__ b,
                                                      float* __restrict__ out) {
  const int gid  = blockIdx.x * 256 + threadIdx.x;
  const int lane = threadIdx.x & 63;
  const int wid  = __builtin_amdgcn_readfirstlane(gid >> 6);
  if (wid >= N_NODES) return;
  const int beg = rowptr[wid];
  const int end = rowptr[wid + 1];
  const bool act = lane < 40;
  const int  l   = act ? lane : 0;
  float acc = 0.f;
  int e = beg;
  for (; e + 4 <= end; e += 4) {
    const unsigned u0 = __builtin_nontemporal_load(se + e + 0);
    const unsigned u1 = __builtin_nontemporal_load(se + e + 1);
    const unsigned u2 = __builtin_nontemporal_load(se + e + 2);
    const unsigned u3 = __builtin_nontemporal_load(se + e + 3);
    const float v0 = __half2float(H[(long)(u0 & 0xFFFF) * 40 + l]);
    const float v1 = __half2float(H[(long)(u1 & 0xFFFF) * 40 + l]);
    const float v2 = __half2float(H[(long)(u2 & 0xFFFF) * 40 + l]);
    const float v3 = __half2float(H[(long)(u3 & 0xFFFF) * 40 + l]);
    acc += dec_w(u0) * v0;
    acc += dec_w(u1) * v1;
    acc += dec_w(u2) * v2;
    acc += dec_w(u3) * v3;
  }
  for (; e < end; ++e) {
    const unsigned u = __builtin_nontemporal_load(se + e);
    acc += dec_w(u) * __half2float(H[(long)(u & 0xFFFF) * 40 + l]);
  }
  if (act) __builtin_nontemporal_store(acc + b[lane], out + (long)wid * 40 + lane);
}

// ========================= BatchNorm stats =========================
constexpr int BN_BLOCKS   = 512;
constexpr int BN_ROWS_PER = (N_NODES + BN_BLOCKS - 1) / BN_BLOCKS;  // 98

__global__ __launch_bounds__(256) void bn_stats_ker(const float* __restrict__ A,
                                                    float* __restrict__ stats) {
  const int tid = threadIdx.x;
  const int c   = tid & 127;
  const int rs  = tid >> 7;
  const int r0  = blockIdx.x * BN_ROWS_PER;
  const int re  = min(r0 + BN_ROWS_PER, N_NODES);
  float s = 0.f, sq = 0.f;
  for (int r = r0 + rs; r < re; r += 2) {
    const float v = A[(long)r * 128 + c];
    s += v; sq += v * v;
  }
  atomicAdd(&stats[c], s);
  atomicAdd(&stats[128 + c], sq);
}

// ---------------------------------------------------------------------------
extern "C" void kernel_launch(void* const* d_in, const int* in_sizes, int n_in,
                              void* d_out, int out_size, void* d_ws, size_t ws_size,
                              hipStream_t stream) {
  const float* x    = (const float*)d_in[0];
  const int*   erow = (const int*)d_in[1];
  const int*   ecol = (const int*)d_in[2];
  const float* ew   = (const float*)d_in[3];
  const float* W0   = (const float*)d_in[4];
  const float* g0   = (const float*)d_in[6];
  const float* be0  = (const float*)d_in[7];
  const float* W1   = (const float*)d_in[8];
  const float* g1   = (const float*)d_in[10];
  const float* be1  = (const float*)d_in[11];
  const float* W2   = (const float*)d_in[12];
  const float* b2   = (const float*)d_in[13];
  float* out = (float*)d_out;

  // workspace layout (16B-aligned sections)
  float*    agg     = (float*)d_ws;                          // N*128 fp32
  __half*   h       = (__half*)(agg + (long)N_NODES * 128);  // N*128 fp16
  float*    stats0  = (float*)(h + (long)N_NODES * 128);     // 256
  float*    stats1  = stats0 + 256;                          // 256
  int*      gcursor = (int*)(stats1 + 256);                  // 256 (bucket counts)
  int*      bbase   = gcursor + 256;                         // 256
  int*      rowptr  = bbase + 256;                           // N+1 (pad 50004)
  unsigned* se      = (unsigned*)(rowptr + 50004);           // E
  int2*     ebuf    = (int2*)(se + E_EDGES);                 // K*BCAP (8B-aligned)

  const int g_gemm128 = (N_NODES + 31) / 32;   // 1563
  const int g_gemm40  = (N_NODES + 95) / 96;   // 521
  const int g_spmm    = (N_NODES * 64) / 256;  // 12500

  // ---- zero stats + bucket cursors in one memset ----
  hipMemsetAsync(stats0, 0, 768 * 4, stream);

  // ---- CSR build: two-phase LDS-binned partition ----
  partA_ker<<<PART_BLK, 256, 0, stream>>>(erow, ecol, ew, gcursor, ebuf);
  bscan_ker<<<1, 256, 0, stream>>>(gcursor, bbase, rowptr);
  partB_ker<<<K_BUCKETS, 256, 0, stream>>>(gcursor, bbase, ebuf, se, rowptr);

  // ---- layer 0 ----
  gemm_ker<128, 32, false><<<g_gemm128, 256, 0, stream>>>(x, W0, h, nullptr, nullptr, nullptr);
  spmm_csr128_ker<<<g_spmm, 256, 0, stream>>>(rowptr, se, h, agg);
  bn_stats_ker<<<BN_BLOCKS, 256, 0, stream>>>(agg, stats0);

  // ---- layer 1 (BN0 finalize+affine+ReLU fused into GEMM input load) ----
  gemm_ker<128, 32, true><<<g_gemm128, 256, 0, stream>>>(agg, W1, h, stats0, g0, be0);
  spmm_csr128_ker<<<g_spmm, 256, 0, stream>>>(rowptr, se, h, agg);
  bn_stats_ker<<<BN_BLOCKS, 256, 0, stream>>>(agg, stats1);

  // ---- layer 2 (BN1 fused into GEMM, bias b2 fused into SpMM) ----
  gemm_ker<40, 96, true><<<g_gemm40, 256, 0, stream>>>(agg, W2, h, stats1, g1, be1);
  spmm_csr40_ker<<<g_spmm, 256, 0, stream>>>(rowptr, se, h, b2, out);
}

// Round 8
// 391.067 us; speedup vs baseline: 1.5881x; 1.2217x over previous
//
#include <hip/hip_runtime.h>
#include <hip/hip_fp16.h>

// ---------------------------------------------------------------------------
// GCN: per-call CSR build via LDS-binned two-phase partition, then
// 3x (MFMA-f16 GEMM -> CSR-SpMM). BN finalize+affine+ReLU fused into next
// GEMM's staging. H gather table fp16. CSR entries 4B (u16 col | fp16 w).
// b0/b1 dropped (cancel in BN mean-subtraction).
// ---------------------------------------------------------------------------

constexpr int   N_NODES   = 50000;
constexpr int   E_EDGES   = 1600000;
constexpr float BN_EPS    = 1e-5f;
constexpr int   K_BUCKETS = (N_NODES + 255) / 256;   // 196
constexpr int   BCAP      = 10240;
constexpr int   CHUNK     = 4096;
constexpr int   PART_BLK  = (E_EDGES + CHUNK - 1) / CHUNK;  // 391

typedef _Float16 f16x8 __attribute__((ext_vector_type(8)));
typedef float    f32x4 __attribute__((ext_vector_type(4)));

__device__ __forceinline__ float dec_w(unsigned u) {
  return __half2float(__ushort_as_half((unsigned short)(u >> 16)));
}

// ========================= partition phase A =========================
__global__ __launch_bounds__(256) void partA_ker(const int* __restrict__ rows,
                                                 const int* __restrict__ cols,
                                                 const float* __restrict__ ew,
                                                 int* __restrict__ gcursor,
                                                 int2* __restrict__ ebuf) {
  __shared__ int  cnt[256], cnt2[256], sc[256], offs[256], gbase[256];
  __shared__ int2 buf[CHUNK];
  const int tid = threadIdx.x;
  cnt[tid] = 0; cnt2[tid] = 0;
  __syncthreads();

  const int e0   = blockIdx.x * CHUNK;
  const int ecnt = min(CHUNK, E_EDGES - e0);

  for (int i = tid; i < ecnt; i += 256)
    atomicAdd(&cnt[rows[e0 + i] >> 8], 1);
  __syncthreads();

  sc[tid] = cnt[tid];
  __syncthreads();
  for (int o = 1; o < 256; o <<= 1) {
    int u = (tid >= o) ? sc[tid - o] : 0;
    __syncthreads();
    sc[tid] += u;
    __syncthreads();
  }
  offs[tid] = sc[tid] - cnt[tid];
  if (tid < K_BUCKETS && cnt[tid] > 0)
    gbase[tid] = atomicAdd(&gcursor[tid], cnt[tid]);
  __syncthreads();

  for (int i = tid; i < ecnt; i += 256) {
    const int   r = rows[e0 + i];
    const int   c = cols[e0 + i];
    const float w = ew[e0 + i];
    const int   b = r >> 8;
    const int   p = offs[b] + atomicAdd(&cnt2[b], 1);
    int2 v;
    v.x = c | ((int)__half_as_ushort(__float2half_rn(w)) << 16);
    v.y = r;
    buf[p] = v;
  }
  __syncthreads();

  for (int i = tid; i < ecnt; i += 256) {
    const int2 v   = buf[i];
    const int  b   = v.y >> 8;
    const int  idx = gbase[b] + (i - offs[b]);
    if (idx < BCAP) ebuf[(long)b * BCAP + idx] = v;
  }
}

// ========================= bucket-base scan =========================
__global__ __launch_bounds__(256) void bscan_ker(const int* __restrict__ gcursor,
                                                 int* __restrict__ bbase,
                                                 int* __restrict__ rowptr) {
  const int t = threadIdx.x;
  const int v = (t < K_BUCKETS) ? gcursor[t] : 0;
  __shared__ int sh[256];
  sh[t] = v;
  __syncthreads();
  for (int o = 1; o < 256; o <<= 1) {
    int u = (t >= o) ? sh[t - o] : 0;
    __syncthreads();
    sh[t] += u;
    __syncthreads();
  }
  bbase[t] = sh[t] - v;
  if (t == 0) rowptr[N_NODES] = E_EDGES;
}

// ========================= partition phase B =========================
__global__ __launch_bounds__(256) void partB_ker(const int* __restrict__ gcursor,
                                                 const int* __restrict__ bbase,
                                                 const int2* __restrict__ ebuf,
                                                 unsigned* __restrict__ se,
                                                 int* __restrict__ rowptr) {
  const int b    = blockIdx.x;
  const int tid  = threadIdx.x;
  const int cntb = min(gcursor[b], BCAP);
  const int base = bbase[b];
  __shared__ int rcnt[256], roff[256], rcur[256], sh[256];
  rcnt[tid] = 0; rcur[tid] = 0;
  __syncthreads();

  const int2* __restrict__ src = ebuf + (long)b * BCAP;
  for (int i = tid; i < cntb; i += 256)
    atomicAdd(&rcnt[src[i].y & 255], 1);
  __syncthreads();

  sh[tid] = rcnt[tid];
  __syncthreads();
  for (int o = 1; o < 256; o <<= 1) {
    int u = (tid >= o) ? sh[tid - o] : 0;
    __syncthreads();
    sh[tid] += u;
    __syncthreads();
  }
  roff[tid] = sh[tid] - rcnt[tid];
  const int grow = b * 256 + tid;
  if (grow < N_NODES) rowptr[grow] = base + roff[tid];
  __syncthreads();

  for (int i = tid; i < cntb; i += 256) {
    const int2 v  = src[i];
    const int  rl = v.y & 255;
    const int  p  = roff[rl] + atomicAdd(&rcur[rl], 1);
    se[base + p] = (unsigned)v.x;
  }
}

// ========================= W prep: Wt[n][k] fp16 =========================
// one block per output feature n (padded rows -> zeros)
__global__ __launch_bounds__(128) void wprep_ker(const float* __restrict__ W,
                                                 __half* __restrict__ Wt,
                                                 int fout) {
  const int n = blockIdx.x;
  const int k = threadIdx.x;
  const float v = (n < fout) ? W[k * fout + n] : 0.f;
  Wt[n * 128 + k] = __float2half_rn(v);
}

// ========================= MFMA GEMM =========================
// H[N][FOUT](fp16) = act(X)[N][128](fp32) @ W ; Wt[n][k] fp16 input.
// Block: 4 waves, 64 rows x FOUT_PAD cols. K=128 via 4x mfma_f32_16x16x32_f16.
// Verified layouts: A[m=lane&15][k=(lane>>4)*8+j]; B-frag = Wt row (like A);
// C/D: col=lane&15, row=(lane>>4)*4+reg.
template <int FOUT, int FOUT_PAD, bool FUSE>
__global__ __launch_bounds__(256) void gemm_mfma_ker(const float* __restrict__ X,
                                                     const __half* __restrict__ Wt,
                                                     __half* __restrict__ H,
                                                     const float* __restrict__ stats,
                                                     const float* __restrict__ g,
                                                     const float* __restrict__ be) {
  constexpr int CT    = FOUT_PAD / 16;  // col tiles per wave
  constexpr int PITCH = 136;            // halves; 272B rows: 16B-aligned, 2-way banks

  __shared__ _Float16 Xs[64 * PITCH];
  __shared__ _Float16 Ws[FOUT_PAD * PITCH];
  __shared__ float ssc[128], ssh[128];

  const int tid  = threadIdx.x;
  const int row0 = blockIdx.x * 64;

  if constexpr (FUSE) {
    if (tid < 128) {
      const float mean = stats[tid] * (1.0f / N_NODES);
      const float var  = stats[128 + tid] * (1.0f / N_NODES) - mean * mean;
      const float sc   = g[tid] * rsqrtf(var + BN_EPS);
      ssc[tid] = sc;
      ssh[tid] = be[tid] - mean * sc;
    }
    __syncthreads();
  }

  // stage Wt (fp16, contiguous rows of 128 -> pitch 136)
  for (int i = tid; i < FOUT_PAD * 16; i += 256) {
    const int r  = i >> 4;
    const int c8 = (i & 15) * 8;
    *(f16x8*)(Ws + r * PITCH + c8) = *(const f16x8*)(Wt + r * 128 + c8);
  }

  // stage X tile: fp32 -> (BN+ReLU) -> fp16
  for (int i = tid; i < 64 * 32; i += 256) {
    const int r  = i >> 5;
    const int k4 = (i & 31) * 4;
    const int gr = min(row0 + r, N_NODES - 1);
    float4 v = *(const float4*)(X + (long)gr * 128 + k4);
    if constexpr (FUSE) {
      v.x = fmaxf(v.x * ssc[k4 + 0] + ssh[k4 + 0], 0.f);
      v.y = fmaxf(v.y * ssc[k4 + 1] + ssh[k4 + 1], 0.f);
      v.z = fmaxf(v.z * ssc[k4 + 2] + ssh[k4 + 2], 0.f);
      v.w = fmaxf(v.w * ssc[k4 + 3] + ssh[k4 + 3], 0.f);
    }
    _Float16* d = Xs + r * PITCH + k4;
    d[0] = (_Float16)v.x; d[1] = (_Float16)v.y;
    d[2] = (_Float16)v.z; d[3] = (_Float16)v.w;
  }
  __syncthreads();

  const int wave = tid >> 6;
  const int lane = tid & 63;
  const int m    = lane & 15;
  const int q    = lane >> 4;
  const int rw   = wave * 16;

  // A fragments: 4 K-steps
  f16x8 af[4];
  {
    const _Float16* ab = Xs + (rw + m) * PITCH + q * 8;
#pragma unroll
    for (int ks = 0; ks < 4; ++ks) af[ks] = *(const f16x8*)(ab + ks * 32);
  }

  f32x4 acc[CT];
#pragma unroll
  for (int ct = 0; ct < CT; ++ct) acc[ct] = (f32x4){0.f, 0.f, 0.f, 0.f};

#pragma unroll
  for (int ct = 0; ct < CT; ++ct) {
    const _Float16* bb = Ws + (ct * 16 + m) * PITCH + q * 8;
#pragma unroll
    for (int ks = 0; ks < 4; ++ks) {
      const f16x8 bf = *(const f16x8*)(bb + ks * 32);
      acc[ct] = __builtin_amdgcn_mfma_f32_16x16x32_f16(af[ks], bf, acc[ct], 0, 0, 0);
    }
  }

  // epilogue: repack via LDS (reuse Xs) then coalesced 16B stores
  __syncthreads();
#pragma unroll
  for (int ct = 0; ct < CT; ++ct) {
#pragma unroll
    for (int reg = 0; reg < 4; ++reg) {
      Xs[(rw + q * 4 + reg) * PITCH + ct * 16 + m] = (_Float16)acc[ct][reg];
    }
  }
  __syncthreads();

  constexpr int C8 = FOUT / 8;  // 16 or 5
  for (int i = tid; i < 64 * C8; i += 256) {
    const int r  = i / C8;
    const int c8 = (i % C8) * 8;
    const int gr = row0 + r;
    if (gr < N_NODES)
      *(f16x8*)((__half*)H + (long)gr * FOUT + c8) = *(const f16x8*)(Xs + r * PITCH + c8);
  }
}

// ========================= CSR SpMM =========================
__global__ __launch_bounds__(256) void spmm_csr128_ker(const int* __restrict__ rowptr,
                                                       const unsigned* __restrict__ se,
                                                       const __half* __restrict__ H,
                                                       float* __restrict__ A) {
  const int gid  = blockIdx.x * 256 + threadIdx.x;
  const int lane = threadIdx.x & 63;
  const int wid  = __builtin_amdgcn_readfirstlane(gid >> 6);
  if (wid >= N_NODES) return;
  const int beg = rowptr[wid];
  const int end = rowptr[wid + 1];
  const __half2* __restrict__ Hl = (const __half2*)H + lane;
  float acc0 = 0.f, acc1 = 0.f;
  int e = beg;
  for (; e + 4 <= end; e += 4) {
    const unsigned u0 = __builtin_nontemporal_load(se + e + 0);
    const unsigned u1 = __builtin_nontemporal_load(se + e + 1);
    const unsigned u2 = __builtin_nontemporal_load(se + e + 2);
    const unsigned u3 = __builtin_nontemporal_load(se + e + 3);
    const float2 v0 = __half22float2(Hl[(long)(u0 & 0xFFFF) * 64]);
    const float2 v1 = __half22float2(Hl[(long)(u1 & 0xFFFF) * 64]);
    const float2 v2 = __half22float2(Hl[(long)(u2 & 0xFFFF) * 64]);
    const float2 v3 = __half22float2(Hl[(long)(u3 & 0xFFFF) * 64]);
    const float w0 = dec_w(u0), w1 = dec_w(u1), w2 = dec_w(u2), w3 = dec_w(u3);
    acc0 += w0 * v0.x; acc1 += w0 * v0.y;
    acc0 += w1 * v1.x; acc1 += w1 * v1.y;
    acc0 += w2 * v2.x; acc1 += w2 * v2.y;
    acc0 += w3 * v3.x; acc1 += w3 * v3.y;
  }
  for (; e < end; ++e) {
    const unsigned u = __builtin_nontemporal_load(se + e);
    const float2 v = __half22float2(Hl[(long)(u & 0xFFFF) * 64]);
    const float  w = dec_w(u);
    acc0 += w * v.x; acc1 += w * v.y;
  }
  *(float2*)(A + (long)wid * 128 + lane * 2) = make_float2(acc0, acc1);
}

__global__ __launch_bounds__(256) void spmm_csr40_ker(const int* __restrict__ rowptr,
                                                      const unsigned* __restrict__ se,
                                                      const __half* __restrict__ H,
                                                      const float* __restrict__ b,
                                                      float* __restrict__ out) {
  const int gid  = blockIdx.x * 256 + threadIdx.x;
  const int lane = threadIdx.x & 63;
  const int wid  = __builtin_amdgcn_readfirstlane(gid >> 6);
  if (wid >= N_NODES) return;
  const int beg = rowptr[wid];
  const int end = rowptr[wid + 1];
  const bool act = lane < 40;
  const int  l   = act ? lane : 0;
  float acc = 0.f;
  int e = beg;
  for (; e + 4 <= end; e += 4) {
    const unsigned u0 = __builtin_nontemporal_load(se + e + 0);
    const unsigned u1 = __builtin_nontemporal_load(se + e + 1);
    const unsigned u2 = __builtin_nontemporal_load(se + e + 2);
    const unsigned u3 = __builtin_nontemporal_load(se + e + 3);
    const float v0 = __half2float(H[(long)(u0 & 0xFFFF) * 40 + l]);
    const float v1 = __half2float(H[(long)(u1 & 0xFFFF) * 40 + l]);
    const float v2 = __half2float(H[(long)(u2 & 0xFFFF) * 40 + l]);
    const float v3 = __half2float(H[(long)(u3 & 0xFFFF) * 40 + l]);
    acc += dec_w(u0) * v0;
    acc += dec_w(u1) * v1;
    acc += dec_w(u2) * v2;
    acc += dec_w(u3) * v3;
  }
  for (; e < end; ++e) {
    const unsigned u = __builtin_nontemporal_load(se + e);
    acc += dec_w(u) * __half2float(H[(long)(u & 0xFFFF) * 40 + l]);
  }
  if (act) __builtin_nontemporal_store(acc + b[lane], out + (long)wid * 40 + lane);
}

// ========================= BatchNorm stats =========================
constexpr int BN_BLOCKS   = 512;
constexpr int BN_ROWS_PER = (N_NODES + BN_BLOCKS - 1) / BN_BLOCKS;  // 98

__global__ __launch_bounds__(256) void bn_stats_ker(const float* __restrict__ A,
                                                    float* __restrict__ stats) {
  const int tid = threadIdx.x;
  const int c   = tid & 127;
  const int rs  = tid >> 7;
  const int r0  = blockIdx.x * BN_ROWS_PER;
  const int re  = min(r0 + BN_ROWS_PER, N_NODES);
  float s = 0.f, sq = 0.f;
  for (int r = r0 + rs; r < re; r += 2) {
    const float v = A[(long)r * 128 + c];
    s += v; sq += v * v;
  }
  atomicAdd(&stats[c], s);
  atomicAdd(&stats[128 + c], sq);
}

// ---------------------------------------------------------------------------
extern "C" void kernel_launch(void* const* d_in, const int* in_sizes, int n_in,
                              void* d_out, int out_size, void* d_ws, size_t ws_size,
                              hipStream_t stream) {
  const float* x    = (const float*)d_in[0];
  const int*   erow = (const int*)d_in[1];
  const int*   ecol = (const int*)d_in[2];
  const float* ew   = (const float*)d_in[3];
  const float* W0   = (const float*)d_in[4];
  const float* g0   = (const float*)d_in[6];
  const float* be0  = (const float*)d_in[7];
  const float* W1   = (const float*)d_in[8];
  const float* g1   = (const float*)d_in[10];
  const float* be1  = (const float*)d_in[11];
  const float* W2   = (const float*)d_in[12];
  const float* b2   = (const float*)d_in[13];
  float* out = (float*)d_out;

  // workspace layout (16B-aligned sections)
  float*    agg     = (float*)d_ws;                          // N*128 fp32
  __half*   h       = (__half*)(agg + (long)N_NODES * 128);  // N*128 fp16
  float*    stats0  = (float*)(h + (long)N_NODES * 128);     // 256
  float*    stats1  = stats0 + 256;                          // 256
  int*      gcursor = (int*)(stats1 + 256);                  // 256
  int*      bbase   = gcursor + 256;                         // 256
  int*      rowptr  = bbase + 256;                           // N+1 (pad 50004)
  unsigned* se      = (unsigned*)(rowptr + 50004);           // E
  int2*     ebuf    = (int2*)(se + E_EDGES);                 // K*BCAP
  __half*   wt0     = (__half*)(ebuf + (long)K_BUCKETS * BCAP);  // 128*128
  __half*   wt1     = wt0 + 128 * 128;                       // 128*128
  __half*   wt2     = wt1 + 128 * 128;                       // 48*128

  const int g_gemm = (N_NODES + 63) / 64;     // 782
  const int g_spmm = (N_NODES * 64) / 256;    // 12500

  hipMemsetAsync(stats0, 0, 768 * 4, stream);  // stats0+stats1+gcursor

  // ---- W prep (independent, tiny) ----
  wprep_ker<<<128, 128, 0, stream>>>(W0, wt0, 128);
  wprep_ker<<<128, 128, 0, stream>>>(W1, wt1, 128);
  wprep_ker<<<48, 128, 0, stream>>>(W2, wt2, 40);

  // ---- CSR build ----
  partA_ker<<<PART_BLK, 256, 0, stream>>>(erow, ecol, ew, gcursor, ebuf);
  bscan_ker<<<1, 256, 0, stream>>>(gcursor, bbase, rowptr);
  partB_ker<<<K_BUCKETS, 256, 0, stream>>>(gcursor, bbase, ebuf, se, rowptr);

  // ---- layer 0 ----
  gemm_mfma_ker<128, 128, false><<<g_gemm, 256, 0, stream>>>(x, wt0, h, nullptr, nullptr, nullptr);
  spmm_csr128_ker<<<g_spmm, 256, 0, stream>>>(rowptr, se, h, agg);
  bn_stats_ker<<<BN_BLOCKS, 256, 0, stream>>>(agg, stats0);

  // ---- layer 1 ----
  gemm_mfma_ker<128, 128, true><<<g_gemm, 256, 0, stream>>>(agg, wt1, h, stats0, g0, be0);
  spmm_csr128_ker<<<g_spmm, 256, 0, stream>>>(rowptr, se, h, agg);
  bn_stats_ker<<<BN_BLOCKS, 256, 0, stream>>>(agg, stats1);

  // ---- layer 2 ----
  gemm_mfma_ker<40, 48, true><<<g_gemm, 256, 0, stream>>>(agg, wt2, h, stats1, g1, be1);
  spmm_csr40_ker<<<g_spmm, 256, 0, stream>>>(rowptr, se, h, b2, out);
}

// Round 9
// 387.652 us; speedup vs baseline: 1.6021x; 1.0088x over previous
//
#include <hip/hip_runtime.h>
#include <hip/hip_fp16.h>

// ---------------------------------------------------------------------------
// GCN: per-call CSR build via LDS-binned two-phase partition (partB also
// col-group-orders each row's edges -> phase-coherent L2 sweep in SpMM),
// then 3x (MFMA-f16 GEMM -> CSR-SpMM). BN finalize+affine+ReLU fused into
// next GEMM's staging. H gather table fp16, agg accumulator stored fp16.
// CSR entries 4B (u16 col | fp16 w). b0/b1 dropped (cancel in BN).
// ---------------------------------------------------------------------------

constexpr int   N_NODES   = 50000;
constexpr int   E_EDGES   = 1600000;
constexpr float BN_EPS    = 1e-5f;
constexpr int   K_BUCKETS = (N_NODES + 255) / 256;   // 196
constexpr int   BCAP      = 10240;
constexpr int   CHUNK     = 4096;
constexpr int   PART_BLK  = (E_EDGES + CHUNK - 1) / CHUNK;  // 391
constexpr int   CG_SHIFT  = 13;   // col-group = 8192 rows = 2MB fp16 H chunk
constexpr int   CG_N      = 8;    // 50000>>13 = 6 -> 7 groups used

typedef _Float16 f16x8 __attribute__((ext_vector_type(8)));
typedef float    f32x4 __attribute__((ext_vector_type(4)));

__device__ __forceinline__ float dec_w(unsigned u) {
  return __half2float(__ushort_as_half((unsigned short)(u >> 16)));
}

// ========================= partition phase A =========================
__global__ __launch_bounds__(256) void partA_ker(const int* __restrict__ rows,
                                                 const int* __restrict__ cols,
                                                 const float* __restrict__ ew,
                                                 int* __restrict__ gcursor,
                                                 int2* __restrict__ ebuf) {
  __shared__ int  cnt[256], cnt2[256], sc[256], offs[256], gbase[256];
  __shared__ int2 buf[CHUNK];
  const int tid = threadIdx.x;
  cnt[tid] = 0; cnt2[tid] = 0;
  __syncthreads();

  const int e0   = blockIdx.x * CHUNK;
  const int ecnt = min(CHUNK, E_EDGES - e0);

  for (int i = tid; i < ecnt; i += 256)
    atomicAdd(&cnt[rows[e0 + i] >> 8], 1);
  __syncthreads();

  sc[tid] = cnt[tid];
  __syncthreads();
  for (int o = 1; o < 256; o <<= 1) {
    int u = (tid >= o) ? sc[tid - o] : 0;
    __syncthreads();
    sc[tid] += u;
    __syncthreads();
  }
  offs[tid] = sc[tid] - cnt[tid];
  if (tid < K_BUCKETS && cnt[tid] > 0)
    gbase[tid] = atomicAdd(&gcursor[tid], cnt[tid]);
  __syncthreads();

  for (int i = tid; i < ecnt; i += 256) {
    const int   r = rows[e0 + i];
    const int   c = cols[e0 + i];
    const float w = ew[e0 + i];
    const int   b = r >> 8;
    const int   p = offs[b] + atomicAdd(&cnt2[b], 1);
    int2 v;
    v.x = c | ((int)__half_as_ushort(__float2half_rn(w)) << 16);
    v.y = r;
    buf[p] = v;
  }
  __syncthreads();

  for (int i = tid; i < ecnt; i += 256) {
    const int2 v   = buf[i];
    const int  b   = v.y >> 8;
    const int  idx = gbase[b] + (i - offs[b]);
    if (idx < BCAP) ebuf[(long)b * BCAP + idx] = v;
  }
}

// ========================= bucket-base scan =========================
__global__ __launch_bounds__(256) void bscan_ker(const int* __restrict__ gcursor,
                                                 int* __restrict__ bbase,
                                                 int* __restrict__ rowptr) {
  const int t = threadIdx.x;
  const int v = (t < K_BUCKETS) ? gcursor[t] : 0;
  __shared__ int sh[256];
  sh[t] = v;
  __syncthreads();
  for (int o = 1; o < 256; o <<= 1) {
    int u = (t >= o) ? sh[t - o] : 0;
    __syncthreads();
    sh[t] += u;
    __syncthreads();
  }
  bbase[t] = sh[t] - v;
  if (t == 0) rowptr[N_NODES] = E_EDGES;
}

// ========================= partition phase B =========================
// One block per bucket. Bins by (row_local, col>>CG_SHIFT): entries land
// row-grouped AND col-group-ordered within the row -> SpMM waves sweep H's
// 2MB chunks in loose phase, keeping the gather working set L2-resident.
__global__ __launch_bounds__(256) void partB_ker(const int* __restrict__ gcursor,
                                                 const int* __restrict__ bbase,
                                                 const int2* __restrict__ ebuf,
                                                 unsigned* __restrict__ se,
                                                 int* __restrict__ rowptr) {
  const int b    = blockIdx.x;
  const int tid  = threadIdx.x;
  const int cntb = min(gcursor[b], BCAP);
  const int base = bbase[b];
  __shared__ int cnt[256 * CG_N], cur[256 * CG_N], sh[256];

#pragma unroll
  for (int j = 0; j < CG_N; ++j) {
    cnt[tid * CG_N + j] = 0;
    cur[tid * CG_N + j] = 0;
  }
  __syncthreads();

  const int2* __restrict__ src = ebuf + (long)b * BCAP;
  for (int i = tid; i < cntb; i += 256) {
    const int2 v = src[i];
    const int key = (v.y & 255) * CG_N + ((v.x & 0xFFFF) >> CG_SHIFT);
    atomicAdd(&cnt[key], 1);
  }
  __syncthreads();

  // serial scan of this thread's row (8 cells) + block scan of totals
  int loc[CG_N];
  int s = 0;
#pragma unroll
  for (int j = 0; j < CG_N; ++j) { loc[j] = s; s += cnt[tid * CG_N + j]; }
  sh[tid] = s;
  __syncthreads();
  for (int o = 1; o < 256; o <<= 1) {
    int u = (tid >= o) ? sh[tid - o] : 0;
    __syncthreads();
    sh[tid] += u;
    __syncthreads();
  }
  const int tb = sh[tid] - s;  // exclusive base for this row within bucket
#pragma unroll
  for (int j = 0; j < CG_N; ++j) cnt[tid * CG_N + j] = tb + loc[j];
  const int grow = b * 256 + tid;
  if (grow < N_NODES) rowptr[grow] = base + tb;
  __syncthreads();

  for (int i = tid; i < cntb; i += 256) {
    const int2 v   = src[i];
    const int  key = (v.y & 255) * CG_N + ((v.x & 0xFFFF) >> CG_SHIFT);
    const int  p   = cnt[key] + atomicAdd(&cur[key], 1);
    se[base + p] = (unsigned)v.x;
  }
}

// ========================= W prep: Wt[n][k] fp16 =========================
__global__ __launch_bounds__(128) void wprep_ker(const float* __restrict__ W,
                                                 __half* __restrict__ Wt,
                                                 int fout) {
  const int n = blockIdx.x;
  const int k = threadIdx.x;
  const float v = (n < fout) ? W[k * fout + n] : 0.f;
  Wt[n * 128 + k] = __float2half_rn(v);
}

// ========================= MFMA GEMM =========================
// H[N][FOUT](fp16) = act(X)[N][128] @ W ; X fp32 (layer 0) or fp16 (agg).
// Block: 4 waves, 64 rows x FOUT_PAD cols. K=128 via 4x mfma_f32_16x16x32_f16.
// A[m=lane&15][k=(lane>>4)*8+j]; B-frag = Wt row; C/D: col=lane&15,
// row=(lane>>4)*4+reg.
template <int FOUT, int FOUT_PAD, bool FUSE, typename XT>
__global__ __launch_bounds__(256) void gemm_mfma_ker(const XT* __restrict__ X,
                                                     const __half* __restrict__ Wt,
                                                     __half* __restrict__ H,
                                                     const float* __restrict__ stats,
                                                     const float* __restrict__ g,
                                                     const float* __restrict__ be) {
  constexpr int CT    = FOUT_PAD / 16;
  constexpr int PITCH = 136;

  __shared__ _Float16 Xs[64 * PITCH];
  __shared__ _Float16 Ws[FOUT_PAD * PITCH];
  __shared__ float ssc[128], ssh[128];

  const int tid  = threadIdx.x;
  const int row0 = blockIdx.x * 64;

  if constexpr (FUSE) {
    if (tid < 128) {
      const float mean = stats[tid] * (1.0f / N_NODES);
      const float var  = stats[128 + tid] * (1.0f / N_NODES) - mean * mean;
      const float sc   = g[tid] * rsqrtf(var + BN_EPS);
      ssc[tid] = sc;
      ssh[tid] = be[tid] - mean * sc;
    }
    __syncthreads();
  }

  for (int i = tid; i < FOUT_PAD * 16; i += 256) {
    const int r  = i >> 4;
    const int c8 = (i & 15) * 8;
    *(f16x8*)(Ws + r * PITCH + c8) = *(const f16x8*)(Wt + r * 128 + c8);
  }

  if constexpr (sizeof(XT) == 4) {  // fp32 input (layer 0, no fuse)
    for (int i = tid; i < 64 * 32; i += 256) {
      const int r  = i >> 5;
      const int k4 = (i & 31) * 4;
      const int gr = min(row0 + r, N_NODES - 1);
      float4 v = *(const float4*)((const float*)X + (long)gr * 128 + k4);
      _Float16* d = Xs + r * PITCH + k4;
      d[0] = (_Float16)v.x; d[1] = (_Float16)v.y;
      d[2] = (_Float16)v.z; d[3] = (_Float16)v.w;
    }
  } else {  // fp16 agg input
    for (int i = tid; i < 64 * 16; i += 256) {
      const int r  = i >> 4;
      const int k8 = (i & 15) * 8;
      const int gr = min(row0 + r, N_NODES - 1);
      f16x8 v = *(const f16x8*)((const _Float16*)X + (long)gr * 128 + k8);
      if constexpr (FUSE) {
#pragma unroll
        for (int j = 0; j < 8; ++j)
          v[j] = (_Float16)fmaxf((float)v[j] * ssc[k8 + j] + ssh[k8 + j], 0.f);
      }
      *(f16x8*)(Xs + r * PITCH + k8) = v;
    }
  }
  __syncthreads();

  const int wave = tid >> 6;
  const int lane = tid & 63;
  const int m    = lane & 15;
  const int q    = lane >> 4;
  const int rw   = wave * 16;

  f16x8 af[4];
  {
    const _Float16* ab = Xs + (rw + m) * PITCH + q * 8;
#pragma unroll
    for (int ks = 0; ks < 4; ++ks) af[ks] = *(const f16x8*)(ab + ks * 32);
  }

  f32x4 acc[CT];
#pragma unroll
  for (int ct = 0; ct < CT; ++ct) acc[ct] = (f32x4){0.f, 0.f, 0.f, 0.f};

#pragma unroll
  for (int ct = 0; ct < CT; ++ct) {
    const _Float16* bb = Ws + (ct * 16 + m) * PITCH + q * 8;
#pragma unroll
    for (int ks = 0; ks < 4; ++ks) {
      const f16x8 bf = *(const f16x8*)(bb + ks * 32);
      acc[ct] = __builtin_amdgcn_mfma_f32_16x16x32_f16(af[ks], bf, acc[ct], 0, 0, 0);
    }
  }

  __syncthreads();
#pragma unroll
  for (int ct = 0; ct < CT; ++ct) {
#pragma unroll
    for (int reg = 0; reg < 4; ++reg) {
      Xs[(rw + q * 4 + reg) * PITCH + ct * 16 + m] = (_Float16)acc[ct][reg];
    }
  }
  __syncthreads();

  constexpr int C8 = FOUT / 8;
  for (int i = tid; i < 64 * C8; i += 256) {
    const int r  = i / C8;
    const int c8 = (i % C8) * 8;
    const int gr = row0 + r;
    if (gr < N_NODES)
      *(f16x8*)((__half*)H + (long)gr * FOUT + c8) = *(const f16x8*)(Xs + r * PITCH + c8);
  }
}

// ========================= CSR SpMM =========================
__global__ __launch_bounds__(256) void spmm_csr128_ker(const int* __restrict__ rowptr,
                                                       const unsigned* __restrict__ se,
                                                       const __half* __restrict__ H,
                                                       __half* __restrict__ A) {
  const int gid  = blockIdx.x * 256 + threadIdx.x;
  const int lane = threadIdx.x & 63;
  const int wid  = __builtin_amdgcn_readfirstlane(gid >> 6);
  if (wid >= N_NODES) return;
  const int beg = rowptr[wid];
  const int end = rowptr[wid + 1];
  const __half2* __restrict__ Hl = (const __half2*)H + lane;
  float acc0 = 0.f, acc1 = 0.f;
  int e = beg;
  for (; e + 4 <= end; e += 4) {
    const unsigned u0 = __builtin_nontemporal_load(se + e + 0);
    const unsigned u1 = __builtin_nontemporal_load(se + e + 1);
    const unsigned u2 = __builtin_nontemporal_load(se + e + 2);
    const unsigned u3 = __builtin_nontemporal_load(se + e + 3);
    const float2 v0 = __half22float2(Hl[(long)(u0 & 0xFFFF) * 64]);
    const float2 v1 = __half22float2(Hl[(long)(u1 & 0xFFFF) * 64]);
    const float2 v2 = __half22float2(Hl[(long)(u2 & 0xFFFF) * 64]);
    const float2 v3 = __half22float2(Hl[(long)(u3 & 0xFFFF) * 64]);
    const float w0 = dec_w(u0), w1 = dec_w(u1), w2 = dec_w(u2), w3 = dec_w(u3);
    acc0 += w0 * v0.x; acc1 += w0 * v0.y;
    acc0 += w1 * v1.x; acc1 += w1 * v1.y;
    acc0 += w2 * v2.x; acc1 += w2 * v2.y;
    acc0 += w3 * v3.x; acc1 += w3 * v3.y;
  }
  for (; e < end; ++e) {
    const unsigned u = __builtin_nontemporal_load(se + e);
    const float2 v = __half22float2(Hl[(long)(u & 0xFFFF) * 64]);
    const float  w = dec_w(u);
    acc0 += w * v.x; acc1 += w * v.y;
  }
  ((__half2*)A)[(long)wid * 64 + lane] = __floats2half2_rn(acc0, acc1);
}

__global__ __launch_bounds__(256) void spmm_csr40_ker(const int* __restrict__ rowptr,
                                                      const unsigned* __restrict__ se,
                                                      const __half* __restrict__ H,
                                                      const float* __restrict__ b,
                                                      float* __restrict__ out) {
  const int gid  = blockIdx.x * 256 + threadIdx.x;
  const int lane = threadIdx.x & 63;
  const int wid  = __builtin_amdgcn_readfirstlane(gid >> 6);
  if (wid >= N_NODES) return;
  const int beg = rowptr[wid];
  const int end = rowptr[wid + 1];
  const bool act = lane < 40;
  const int  l   = act ? lane : 0;
  float acc = 0.f;
  int e = beg;
  for (; e + 4 <= end; e += 4) {
    const unsigned u0 = __builtin_nontemporal_load(se + e + 0);
    const unsigned u1 = __builtin_nontemporal_load(se + e + 1);
    const unsigned u2 = __builtin_nontemporal_load(se + e + 2);
    const unsigned u3 = __builtin_nontemporal_load(se + e + 3);
    const float v0 = __half2float(H[(long)(u0 & 0xFFFF) * 40 + l]);
    const float v1 = __half2float(H[(long)(u1 & 0xFFFF) * 40 + l]);
    const float v2 = __half2float(H[(long)(u2 & 0xFFFF) * 40 + l]);
    const float v3 = __half2float(H[(long)(u3 & 0xFFFF) * 40 + l]);
    acc += dec_w(u0) * v0;
    acc += dec_w(u1) * v1;
    acc += dec_w(u2) * v2;
    acc += dec_w(u3) * v3;
  }
  for (; e < end; ++e) {
    const unsigned u = __builtin_nontemporal_load(se + e);
    acc += dec_w(u) * __half2float(H[(long)(u & 0xFFFF) * 40 + l]);
  }
  if (act) __builtin_nontemporal_store(acc + b[lane], out + (long)wid * 40 + lane);
}

// ========================= BatchNorm stats (fp16 input) =========================
constexpr int BN_BLOCKS   = 512;
constexpr int BN_ROWS_PER = (N_NODES + BN_BLOCKS - 1) / BN_BLOCKS;  // 98

__global__ __launch_bounds__(256) void bn_stats_ker(const __half* __restrict__ A,
                                                    float* __restrict__ stats) {
  const int tid = threadIdx.x;
  const int c   = tid & 127;
  const int rs  = tid >> 7;
  const int r0  = blockIdx.x * BN_ROWS_PER;
  const int re  = min(r0 + BN_ROWS_PER, N_NODES);
  float s = 0.f, sq = 0.f;
  for (int r = r0 + rs; r < re; r += 2) {
    const float v = __half2float(A[(long)r * 128 + c]);
    s += v; sq += v * v;
  }
  atomicAdd(&stats[c], s);
  atomicAdd(&stats[128 + c], sq);
}

// ---------------------------------------------------------------------------
extern "C" void kernel_launch(void* const* d_in, const int* in_sizes, int n_in,
                              void* d_out, int out_size, void* d_ws, size_t ws_size,
                              hipStream_t stream) {
  const float* x    = (const float*)d_in[0];
  const int*   erow = (const int*)d_in[1];
  const int*   ecol = (const int*)d_in[2];
  const float* ew   = (const float*)d_in[3];
  const float* W0   = (const float*)d_in[4];
  const float* g0   = (const float*)d_in[6];
  const float* be0  = (const float*)d_in[7];
  const float* W1   = (const float*)d_in[8];
  const float* g1   = (const float*)d_in[10];
  const float* be1  = (const float*)d_in[11];
  const float* W2   = (const float*)d_in[12];
  const float* b2   = (const float*)d_in[13];
  float* out = (float*)d_out;

  // workspace layout (16B-aligned sections)
  __half*   h       = (__half*)d_ws;                         // N*128 fp16
  __half*   agg     = h + (long)N_NODES * 128;               // N*128 fp16
  float*    stats0  = (float*)(agg + (long)N_NODES * 128);   // 256
  float*    stats1  = stats0 + 256;                          // 256
  int*      gcursor = (int*)(stats1 + 256);                  // 256
  int*      bbase   = gcursor + 256;                         // 256
  int*      rowptr  = bbase + 256;                           // N+1 (pad 50004)
  unsigned* se      = (unsigned*)(rowptr + 50004);           // E
  int2*     ebuf    = (int2*)(se + E_EDGES);                 // K*BCAP
  __half*   wt0     = (__half*)(ebuf + (long)K_BUCKETS * BCAP);  // 128*128
  __half*   wt1     = wt0 + 128 * 128;                       // 128*128
  __half*   wt2     = wt1 + 128 * 128;                       // 48*128

  const int g_gemm = (N_NODES + 63) / 64;     // 782
  const int g_spmm = (N_NODES * 64) / 256;    // 12500

  hipMemsetAsync(stats0, 0, 768 * 4, stream);  // stats0+stats1+gcursor

  // ---- W prep (independent, tiny) ----
  wprep_ker<<<128, 128, 0, stream>>>(W0, wt0, 128);
  wprep_ker<<<128, 128, 0, stream>>>(W1, wt1, 128);
  wprep_ker<<<48, 128, 0, stream>>>(W2, wt2, 40);

  // ---- CSR build ----
  partA_ker<<<PART_BLK, 256, 0, stream>>>(erow, ecol, ew, gcursor, ebuf);
  bscan_ker<<<1, 256, 0, stream>>>(gcursor, bbase, rowptr);
  partB_ker<<<K_BUCKETS, 256, 0, stream>>>(gcursor, bbase, ebuf, se, rowptr);

  // ---- layer 0 ----
  gemm_mfma_ker<128, 128, false><<<g_gemm, 256, 0, stream>>>(x, wt0, h, nullptr, nullptr, nullptr);
  spmm_csr128_ker<<<g_spmm, 256, 0, stream>>>(rowptr, se, h, agg);
  bn_stats_ker<<<BN_BLOCKS, 256, 0, stream>>>(agg, stats0);

  // ---- layer 1 ----
  gemm_mfma_ker<128, 128, true><<<g_gemm, 256, 0, stream>>>((const __half*)agg, wt1, h, stats0, g0, be0);
  spmm_csr128_ker<<<g_spmm, 256, 0, stream>>>(rowptr, se, h, agg);
  bn_stats_ker<<<BN_BLOCKS, 256, 0, stream>>>(agg, stats1);

  // ---- layer 2 ----
  gemm_mfma_ker<40, 48, true><<<g_gemm, 256, 0, stream>>>((const __half*)agg, wt2, h, stats1, g1, be1);
  spmm_csr40_ker<<<g_spmm, 256, 0, stream>>>(rowptr, se, h, b2, out);
}